// Round 1
// baseline (1108.872 us; speedup 1.0000x reference)
//
#include <hip/hip_runtime.h>
#include <hip/hip_bf16.h>
#include <stdint.h>

#define DIM    4096
#define NH     32
#define NKVH   8
#define HD     128
#define SEQ    2048
#define BATCH  2
#define MTOT   (BATCH*SEQ)      // 4096
#define SCALE  0.08838834764831845f

typedef __bf16 bf16_t;
typedef __bf16 bf16x8 __attribute__((ext_vector_type(8)));
typedef float  f32x4  __attribute__((ext_vector_type(4)));

#define AS1 __attribute__((address_space(1)))
#define AS3 __attribute__((address_space(3)))

__device__ __forceinline__ void gload_lds16(const void* g, void* l) {
    __builtin_amdgcn_global_load_lds((const AS1 void*)g, (AS3 void*)l, 16, 0, 0);
}

// ---------------- f32 -> bf16 convert (vectorized) ----------------
__global__ __launch_bounds__(256)
void cvt_f32_bf16(const float* __restrict__ in, bf16_t* __restrict__ out, int n4) {
    for (int i = blockIdx.x * blockDim.x + threadIdx.x; i < n4;
         i += gridDim.x * blockDim.x) {
        float4 v = reinterpret_cast<const float4*>(in)[i];
        union { bf16_t b[4]; uint2 u; } t;
        t.b[0] = (bf16_t)v.x; t.b[1] = (bf16_t)v.y;
        t.b[2] = (bf16_t)v.z; t.b[3] = (bf16_t)v.w;
        reinterpret_cast<uint2*>(out)[i] = t.u;
    }
}

// ---------------- GEMM: out[m][n] = sum_k A[m][k] * W[n][k] ----------------
// 128x128 tile, BK=64, 4 waves (2x2), wave tile 64x64 = 4x4 frags of 16x16x32.
// MODE 0: plain f32 out (row-major [M][DIM])
// MODE 1: Q: rope + relayout to Qr[b][h][s][d] bf16
// MODE 2: fused K|V: blockIdx.y<8 -> K rope+relayout Kr[b][kvh][s][d],
//                    else        -> V transpose     Vt[b][kvh][d][s]
template<int MODE>
__global__ __launch_bounds__(256)
void gemm_bt(const bf16_t* __restrict__ A,
             const bf16_t* __restrict__ B0,
             const bf16_t* __restrict__ B1,
             int K,
             float* __restrict__ outF,
             bf16_t* __restrict__ outQ,
             bf16_t* __restrict__ outV,
             const float* __restrict__ cosT,
             const float* __restrict__ sinT) {
    __shared__ __align__(16) bf16_t As[128 * 64];
    __shared__ __align__(16) bf16_t Bs[128 * 64];

    const int tid = threadIdx.x;
    const int l = tid & 63;
    const int w = tid >> 6;
    const int wr = w >> 1, wc = w & 1;
    const int lr = l & 15, lg = l >> 4;

    const int rowBase = blockIdx.x * 128;
    const int ct = blockIdx.y;

    const bf16_t* Bp;
    if (MODE == 2) {
        Bp = (ct < 8) ? (B0 + (size_t)ct * 128 * K)
                      : (B1 + (size_t)(ct - 8) * 128 * K);
    } else {
        Bp = B0 + (size_t)ct * 128 * K;
    }

    f32x4 acc[4][4] = {};

    for (int kt = 0; kt < K; kt += 64) {
        // stage A and B tiles: 16 KB each via global_load_lds (linear dest)
        for (int t = 0; t < 4; ++t) {
            int s = t * 256 + tid;       // slot; LDS byte off = s*16
            int r = s >> 3;
            int c = (s & 7) * 8;
            gload_lds16(A + (size_t)(rowBase + r) * K + kt + c,
                        As + (size_t)(t * 256 + w * 64) * 8);
            gload_lds16(Bp + (size_t)r * K + kt + c,
                        Bs + (size_t)(t * 256 + w * 64) * 8);
        }
        __syncthreads();

        for (int kk = 0; kk < 2; ++kk) {
            bf16x8 a[4], b[4];
#pragma unroll
            for (int mi = 0; mi < 4; ++mi)
                a[mi] = *(const bf16x8*)(As + (wr * 64 + mi * 16 + lr) * 64 + kk * 32 + lg * 8);
#pragma unroll
            for (int ni = 0; ni < 4; ++ni)
                b[ni] = *(const bf16x8*)(Bs + (wc * 64 + ni * 16 + lr) * 64 + kk * 32 + lg * 8);
#pragma unroll
            for (int mi = 0; mi < 4; ++mi)
#pragma unroll
                for (int ni = 0; ni < 4; ++ni)
                    acc[mi][ni] = __builtin_amdgcn_mfma_f32_16x16x32_bf16(
                        a[mi], b[ni], acc[mi][ni], 0, 0, 0);
        }
        __syncthreads();
    }

    // ---- epilogue ----
#pragma unroll
    for (int mi = 0; mi < 4; ++mi) {
        int gmBase = rowBase + wr * 64 + mi * 16 + lg * 4;
#pragma unroll
        for (int ni = 0; ni < 4; ++ni) {
            f32x4 v4 = acc[mi][ni];
            int gn = ct * 128 + wc * 64 + ni * 16 + lr;
            if (MODE == 0) {
#pragma unroll
                for (int i = 0; i < 4; ++i)
                    outF[(size_t)(gmBase + i) * DIM + gn] = v4[i];
            } else if (MODE == 1) {
                int h = gn >> 7, d = gn & 127, pi2 = d >> 1;
#pragma unroll
                for (int i = 0; i < 4; ++i) {
                    float v = v4[i];
                    float pvv = __shfl_xor(v, 1);
                    int gm = gmBase + i;
                    int bb = gm >> 11, sidx = gm & (SEQ - 1);
                    float c = cosT[sidx * 64 + pi2], sn = sinT[sidx * 64 + pi2];
                    float o = (d & 1) ? (pvv * sn + v * c) : (v * c - pvv * sn);
                    outQ[((size_t)(bb * NH + h) * SEQ + sidx) * HD + d] = (bf16_t)o;
                }
            } else { // MODE 2
                if (ct < 8) { // K path: gn in [0,1024)
                    int h = gn >> 7, d = gn & 127, pi2 = d >> 1;
#pragma unroll
                    for (int i = 0; i < 4; ++i) {
                        float v = v4[i];
                        float pvv = __shfl_xor(v, 1);
                        int gm = gmBase + i;
                        int bb = gm >> 11, sidx = gm & (SEQ - 1);
                        float c = cosT[sidx * 64 + pi2], sn = sinT[sidx * 64 + pi2];
                        float o = (d & 1) ? (pvv * sn + v * c) : (v * c - pvv * sn);
                        outQ[((size_t)(bb * NKVH + h) * SEQ + sidx) * HD + d] = (bf16_t)o;
                    } 
                } else {      // V path
                    int gnv = (ct - 8) * 128 + wc * 64 + ni * 16 + lr;
                    int kvh = gnv >> 7, d = gnv & 127;
#pragma unroll
                    for (int i = 0; i < 4; ++i) {
                        // shfl to keep lane participation uniform with K path
                        float dummy = __shfl_xor(v4[i], 1); (void)dummy;
                        int gm = gmBase + i;
                        int bb = gm >> 11, sidx = gm & (SEQ - 1);
                        outV[((size_t)(bb * NKVH + kvh) * HD + d) * SEQ + sidx] = (bf16_t)v4[i];
                    }
                }
            }
        }
    }
}

// ---------------- flash attention (causal, GQA) ----------------
// grid: B*NH*(SEQ/64) blocks, 256 threads (4 waves).
// Each wave: 16 q-rows; Q in registers; KV tiles of 32 staged in LDS.
__global__ __launch_bounds__(256)
void attn_fwd(const bf16_t* __restrict__ Qr,
              const bf16_t* __restrict__ Kr,
              const bf16_t* __restrict__ Vt,
              bf16_t* __restrict__ Ob) {
    __shared__ __align__(16) bf16_t Ks[32 * 128];   // [kv][d]
    __shared__ __align__(16) bf16_t Vs[128 * 32];   // [d][kv]
    __shared__ __align__(16) bf16_t Ps[4][16 * 32]; // per-wave P

    const int tid = threadIdx.x;
    const int l = tid & 63;
    const int w = tid >> 6;
    const int lr = l & 15, lg = l >> 4;

    const int qt = blockIdx.x & 31;        // SEQ/64 = 32
    const int bh = blockIdx.x >> 5;
    const int b = bh >> 5;                 // NH = 32
    const int h = bh & 31;
    const int kvh = h >> 2;                // n_rep = 4
    const int q0 = qt * 64;

    // Q fragments in registers (4 k-slabs of 32)
    bf16x8 qf[4];
    const bf16_t* qbase = Qr + ((size_t)(b * NH + h) * SEQ + q0 + w * 16 + lr) * HD;
#pragma unroll
    for (int kk = 0; kk < 4; ++kk)
        qf[kk] = *(const bf16x8*)(qbase + kk * 32 + lg * 8);

    f32x4 oacc[8] = {};
    float mrow[4], lsum[4];
#pragma unroll
    for (int i = 0; i < 4; ++i) { mrow[i] = -1e30f; lsum[i] = 0.f; }

    const int nt = (q0 >> 5) + 2;
    const bf16_t* kbase = Kr + (size_t)(b * NKVH + kvh) * SEQ * HD;
    const bf16_t* vbase = Vt + (size_t)(b * NKVH + kvh) * HD * SEQ;

    for (int t = 0; t < nt; ++t) {
        // stage K [32][128] and V^T [128][32] tiles (8 KB each)
        for (int t2 = 0; t2 < 2; ++t2) {
            int s = t2 * 256 + tid;
            int rk = s >> 4, ck = (s & 15) * 8;
            gload_lds16(kbase + (size_t)(t * 32 + rk) * HD + ck,
                        Ks + (size_t)(t2 * 256 + w * 64) * 8);
            int rv = s >> 2, cv = (s & 3) * 8;
            gload_lds16(vbase + (size_t)rv * SEQ + t * 32 + cv,
                        Vs + (size_t)(t2 * 256 + w * 64) * 8);
        }
        __syncthreads();

        bool active = (t * 32) <= (q0 + w * 16 + 15);
        if (active) {
            // QK^T: S[16 q][32 kv]
            f32x4 sf[2] = {};
#pragma unroll
            for (int nf = 0; nf < 2; ++nf)
#pragma unroll
                for (int kk = 0; kk < 4; ++kk) {
                    bf16x8 kf = *(const bf16x8*)(Ks + (nf * 16 + lr) * 128 + kk * 32 + lg * 8);
                    sf[nf] = __builtin_amdgcn_mfma_f32_16x16x32_bf16(qf[kk], kf, sf[nf], 0, 0, 0);
                }

            float pv[2][4];
#pragma unroll
            for (int i = 0; i < 4; ++i) {
                int qrow = q0 + w * 16 + lg * 4 + i;
                float best = -1e30f;
#pragma unroll
                for (int nf = 0; nf < 2; ++nf) {
                    int kvcol = t * 32 + nf * 16 + lr;
                    float sc = sf[nf][i] * SCALE;
                    if (kvcol > qrow) sc = -1e30f;
                    pv[nf][i] = sc;
                    best = fmaxf(best, sc);
                }
#pragma unroll
                for (int off = 1; off < 16; off <<= 1)
                    best = fmaxf(best, __shfl_xor(best, off));
                float mnew = fmaxf(mrow[i], best);
                float alpha = __expf(mrow[i] - mnew);
                float rs = 0.f;
#pragma unroll
                for (int nf = 0; nf < 2; ++nf) {
                    float p = __expf(pv[nf][i] - mnew);
                    pv[nf][i] = p;
                    rs += p;
                }
#pragma unroll
                for (int off = 1; off < 16; off <<= 1)
                    rs += __shfl_xor(rs, off);
                lsum[i] = lsum[i] * alpha + rs;
                mrow[i] = mnew;
#pragma unroll
                for (int df = 0; df < 8; ++df) oacc[df][i] *= alpha;
            }

            // route P through per-wave LDS into A-fragment layout
#pragma unroll
            for (int nf = 0; nf < 2; ++nf)
#pragma unroll
                for (int i = 0; i < 4; ++i)
                    Ps[w][(lg * 4 + i) * 32 + nf * 16 + lr] = (bf16_t)pv[nf][i];
            asm volatile("s_waitcnt lgkmcnt(0)" ::: "memory");
            bf16x8 pf = *(const bf16x8*)(&Ps[w][lr * 32 + lg * 8]);

            // PV: O[16 q][128 d]
#pragma unroll
            for (int df = 0; df < 8; ++df) {
                bf16x8 vf = *(const bf16x8*)(Vs + (df * 16 + lr) * 32 + lg * 8);
                oacc[df] = __builtin_amdgcn_mfma_f32_16x16x32_bf16(pf, vf, oacc[df], 0, 0, 0);
            }
        }
        __syncthreads();
    }

    // epilogue: normalize, write Ob[m][h*HD+d] bf16
#pragma unroll
    for (int df = 0; df < 8; ++df)
#pragma unroll
        for (int i = 0; i < 4; ++i) {
            float o = oacc[df][i] / lsum[i];
            int gm = b * SEQ + q0 + w * 16 + lg * 4 + i;
            int gn = h * HD + df * 16 + lr;
            Ob[(size_t)gm * DIM + gn] = (bf16_t)o;
        }
}

// ---------------- launcher ----------------
extern "C" void kernel_launch(void* const* d_in, const int* in_sizes, int n_in,
                              void* d_out, int out_size, void* d_ws, size_t ws_size,
                              hipStream_t stream) {
    const float* x    = (const float*)d_in[0];
    const float* cosT = (const float*)d_in[1];
    const float* sinT = (const float*)d_in[2];
    const float* wq   = (const float*)d_in[3];
    const float* wk   = (const float*)d_in[4];
    const float* wv   = (const float*)d_in[5];
    const float* wo   = (const float*)d_in[6];

    bf16_t* p = (bf16_t*)d_ws;
    bf16_t* xb  = p; p += (size_t)MTOT * DIM;
    bf16_t* wqb = p; p += (size_t)DIM * DIM;
    bf16_t* wkb = p; p += (size_t)NKVH * HD * DIM;
    bf16_t* wvb = p; p += (size_t)NKVH * HD * DIM;
    bf16_t* wob = p; p += (size_t)DIM * DIM;
    bf16_t* Qr  = p; p += (size_t)MTOT * DIM;
    bf16_t* Kr  = p; p += (size_t)BATCH * NKVH * SEQ * HD;
    bf16_t* Vt  = p; p += (size_t)BATCH * NKVH * HD * SEQ;
    bf16_t* Ob  = p; p += (size_t)MTOT * DIM;
    // total ~160 MiB of d_ws

    cvt_f32_bf16<<<1024, 256, 0, stream>>>(x,  xb,  MTOT * DIM / 4);
    cvt_f32_bf16<<<1024, 256, 0, stream>>>(wq, wqb, DIM * DIM / 4);
    cvt_f32_bf16<<<512,  256, 0, stream>>>(wk, wkb, NKVH * HD * DIM / 4);
    cvt_f32_bf16<<<512,  256, 0, stream>>>(wv, wvb, NKVH * HD * DIM / 4);
    cvt_f32_bf16<<<1024, 256, 0, stream>>>(wo, wob, DIM * DIM / 4);

    gemm_bt<1><<<dim3(MTOT / 128, DIM / 128), 256, 0, stream>>>(
        xb, wqb, nullptr, DIM, nullptr, Qr, nullptr, cosT, sinT);
    gemm_bt<2><<<dim3(MTOT / 128, 16), 256, 0, stream>>>(
        xb, wkb, wvb, DIM, nullptr, Kr, Vt, cosT, sinT);

    attn_fwd<<<BATCH * NH * (SEQ / 64), 256, 0, stream>>>(Qr, Kr, Vt, Ob);

    gemm_bt<0><<<dim3(MTOT / 128, DIM / 128), 256, 0, stream>>>(
        Ob, wob, nullptr, DIM, (float*)d_out, nullptr, nullptr, nullptr, nullptr);
}

// Round 2
// 682.620 us; speedup vs baseline: 1.6244x; 1.6244x over previous
//
#include <hip/hip_runtime.h>
#include <hip/hip_bf16.h>
#include <stdint.h>

#define DIM    4096
#define NH     32
#define NKVH   8
#define HD     128
#define SEQ    2048
#define BATCH  2
#define MTOT   (BATCH*SEQ)      // 4096
#define SCALE  0.08838834764831845f

typedef __bf16 bf16_t;
typedef __bf16 bf16x8 __attribute__((ext_vector_type(8)));
typedef float  f32x4  __attribute__((ext_vector_type(4)));

#define AS1 __attribute__((address_space(1)))
#define AS3 __attribute__((address_space(3)))

__device__ __forceinline__ void gload_lds16(const void* g, void* l) {
    __builtin_amdgcn_global_load_lds((const AS1 void*)g, (AS3 void*)l, 16, 0, 0);
}

// ---------------- f32 -> bf16 convert (vectorized) ----------------
__global__ __launch_bounds__(256)
void cvt_f32_bf16(const float* __restrict__ in, bf16_t* __restrict__ out, int n4) {
    for (int i = blockIdx.x * blockDim.x + threadIdx.x; i < n4;
         i += gridDim.x * blockDim.x) {
        float4 v = reinterpret_cast<const float4*>(in)[i];
        union { bf16_t b[4]; uint2 u; } t;
        t.b[0] = (bf16_t)v.x; t.b[1] = (bf16_t)v.y;
        t.b[2] = (bf16_t)v.z; t.b[3] = (bf16_t)v.w;
        reinterpret_cast<uint2*>(out)[i] = t.u;
    }
}

// ---------------- GEMM: out[m][n] = sum_k A[m][k] * W[n][k] ----------------
// (unchanged from round 1)
template<int MODE>
__global__ __launch_bounds__(256)
void gemm_bt(const bf16_t* __restrict__ A,
             const bf16_t* __restrict__ B0,
             const bf16_t* __restrict__ B1,
             int K,
             float* __restrict__ outF,
             bf16_t* __restrict__ outQ,
             bf16_t* __restrict__ outV,
             const float* __restrict__ cosT,
             const float* __restrict__ sinT) {
    __shared__ __align__(16) bf16_t As[128 * 64];
    __shared__ __align__(16) bf16_t Bs[128 * 64];

    const int tid = threadIdx.x;
    const int l = tid & 63;
    const int w = tid >> 6;
    const int wr = w >> 1, wc = w & 1;
    const int lr = l & 15, lg = l >> 4;

    const int rowBase = blockIdx.x * 128;
    const int ct = blockIdx.y;

    const bf16_t* Bp;
    if (MODE == 2) {
        Bp = (ct < 8) ? (B0 + (size_t)ct * 128 * K)
                      : (B1 + (size_t)(ct - 8) * 128 * K);
    } else {
        Bp = B0 + (size_t)ct * 128 * K;
    }

    f32x4 acc[4][4] = {};

    for (int kt = 0; kt < K; kt += 64) {
        for (int t = 0; t < 4; ++t) {
            int s = t * 256 + tid;
            int r = s >> 3;
            int c = (s & 7) * 8;
            gload_lds16(A + (size_t)(rowBase + r) * K + kt + c,
                        As + (size_t)(t * 256 + w * 64) * 8);
            gload_lds16(Bp + (size_t)r * K + kt + c,
                        Bs + (size_t)(t * 256 + w * 64) * 8);
        }
        __syncthreads();

        for (int kk = 0; kk < 2; ++kk) {
            bf16x8 a[4], b[4];
#pragma unroll
            for (int mi = 0; mi < 4; ++mi)
                a[mi] = *(const bf16x8*)(As + (wr * 64 + mi * 16 + lr) * 64 + kk * 32 + lg * 8);
#pragma unroll
            for (int ni = 0; ni < 4; ++ni)
                b[ni] = *(const bf16x8*)(Bs + (wc * 64 + ni * 16 + lr) * 64 + kk * 32 + lg * 8);
#pragma unroll
            for (int mi = 0; mi < 4; ++mi)
#pragma unroll
                for (int ni = 0; ni < 4; ++ni)
                    acc[mi][ni] = __builtin_amdgcn_mfma_f32_16x16x32_bf16(
                        a[mi], b[ni], acc[mi][ni], 0, 0, 0);
        }
        __syncthreads();
    }

#pragma unroll
    for (int mi = 0; mi < 4; ++mi) {
        int gmBase = rowBase + wr * 64 + mi * 16 + lg * 4;
#pragma unroll
        for (int ni = 0; ni < 4; ++ni) {
            f32x4 v4 = acc[mi][ni];
            int gn = ct * 128 + wc * 64 + ni * 16 + lr;
            if (MODE == 0) {
#pragma unroll
                for (int i = 0; i < 4; ++i)
                    outF[(size_t)(gmBase + i) * DIM + gn] = v4[i];
            } else if (MODE == 1) {
                int h = gn >> 7, d = gn & 127, pi2 = d >> 1;
#pragma unroll
                for (int i = 0; i < 4; ++i) {
                    float v = v4[i];
                    float pvv = __shfl_xor(v, 1);
                    int gm = gmBase + i;
                    int bb = gm >> 11, sidx = gm & (SEQ - 1);
                    float c = cosT[sidx * 64 + pi2], sn = sinT[sidx * 64 + pi2];
                    float o = (d & 1) ? (pvv * sn + v * c) : (v * c - pvv * sn);
                    outQ[((size_t)(bb * NH + h) * SEQ + sidx) * HD + d] = (bf16_t)o;
                }
            } else { // MODE 2
                if (ct < 8) {
                    int h = gn >> 7, d = gn & 127, pi2 = d >> 1;
#pragma unroll
                    for (int i = 0; i < 4; ++i) {
                        float v = v4[i];
                        float pvv = __shfl_xor(v, 1);
                        int gm = gmBase + i;
                        int bb = gm >> 11, sidx = gm & (SEQ - 1);
                        float c = cosT[sidx * 64 + pi2], sn = sinT[sidx * 64 + pi2];
                        float o = (d & 1) ? (pvv * sn + v * c) : (v * c - pvv * sn);
                        outQ[((size_t)(bb * NKVH + h) * SEQ + sidx) * HD + d] = (bf16_t)o;
                    } 
                } else {
                    int gnv = (ct - 8) * 128 + wc * 64 + ni * 16 + lr;
                    int kvh = gnv >> 7, d = gnv & 127;
#pragma unroll
                    for (int i = 0; i < 4; ++i) {
                        float dummy = __shfl_xor(v4[i], 1); (void)dummy;
                        int gm = gmBase + i;
                        int bb = gm >> 11, sidx = gm & (SEQ - 1);
                        outV[((size_t)(bb * NKVH + kvh) * HD + d) * SEQ + sidx] = (bf16_t)v4[i];
                    }
                }
            }
        }
    }
}

// ---------------- flash attention (causal, GQA) ----------------
// grid: 1024 blocks (16 q-tiles x 64 bh), 256 threads (4 waves).
// q-tile = 128 rows; wave owns 32 q rows (2 mi frags); KV tile = 64,
// double-buffered, XOR-swizzled LDS; swapped QK^T (mfma(K,Q)) so softmax
// is lane-local per q-row; P -> LDS via packed b64 swizzled writes.
__global__ __launch_bounds__(256, 2)
void attn_fwd(const bf16_t* __restrict__ Qr,
              const bf16_t* __restrict__ Kr,
              const bf16_t* __restrict__ Vt,
              bf16_t* __restrict__ Ob) {
    __shared__ __align__(16) bf16_t Ks[2][64 * 128];   // [kv][d], swizzled
    __shared__ __align__(16) bf16_t Vs[2][128 * 64];   // [d][kv], swizzled
    __shared__ __align__(16) bf16_t Ps[4][32 * 64];    // per-wave P, swizzled

    const int tid = threadIdx.x;
    const int l  = tid & 63;
    const int w  = tid >> 6;
    const int lr = l & 15, lg = l >> 4;
    const int e  = lr & 7;                 // swizzle key (row&7 for all reads)

    const int qt  = 15 - (blockIdx.x >> 6); // descending work order
    const int bh  = blockIdx.x & 63;
    const int b   = bh >> 5;
    const int h   = bh & 31;
    const int kvh = h >> 2;
    const int q0  = qt * 128;
    const int nt  = 2 * qt + 2;
    const int qmin = q0 + w * 32;

    const bf16_t* kbase = Kr + (size_t)(b * NKVH + kvh) * SEQ * HD;
    const bf16_t* vbase = Vt + (size_t)(b * NKVH + kvh) * HD * SEQ;

    // Q fragments in registers: q = qmin + mi*16 + lr, 4 k-slabs of 32
    bf16x8 qf[2][4];
    const bf16_t* qp = Qr + ((size_t)(b * NH + h) * SEQ + qmin + lr) * HD;
#pragma unroll
    for (int mi = 0; mi < 2; ++mi)
#pragma unroll
        for (int kk = 0; kk < 4; ++kk)
            qf[mi][kk] = *(const bf16x8*)(qp + (size_t)mi * 16 * HD + kk * 32 + lg * 8);

    f32x4 oacc[2][8] = {};
    float mrow[2] = {-1e30f, -1e30f};
    float lsum[2] = {0.f, 0.f};

    // prologue stage tile 0 into buffer 0
#pragma unroll
    for (int t2 = 0; t2 < 4; ++t2) {
        int s = t2 * 256 + tid;
        { int r = s >> 4, g = (s & 15) ^ (r & 7);
          gload_lds16(kbase + (size_t)r * HD + g * 8,
                      &Ks[0][(size_t)(t2 * 256 + w * 64) * 8]); }
        { int r = s >> 3, g = (s & 7) ^ (r & 7);
          gload_lds16(vbase + (size_t)r * SEQ + g * 8,
                      &Vs[0][(size_t)(t2 * 256 + w * 64) * 8]); }
    }
    __syncthreads();

    int cur = 0;
    for (int t = 0; t < nt; ++t) {
        // stage next tile into other buffer (overlaps with compute below)
        if (t + 1 < nt) {
            const int kv1 = (t + 1) * 64;
#pragma unroll
            for (int t2 = 0; t2 < 4; ++t2) {
                int s = t2 * 256 + tid;
                { int r = s >> 4, g = (s & 15) ^ (r & 7);
                  gload_lds16(kbase + (size_t)(kv1 + r) * HD + g * 8,
                              &Ks[cur ^ 1][(size_t)(t2 * 256 + w * 64) * 8]); }
                { int r = s >> 3, g = (s & 7) ^ (r & 7);
                  gload_lds16(vbase + (size_t)r * SEQ + kv1 + g * 8,
                              &Vs[cur ^ 1][(size_t)(t2 * 256 + w * 64) * 8]); }
            }
        }

        const bool active = (t * 64) <= (qmin + 31);
        if (active) {
            const bool needMask = (t * 64 + 63) > qmin;

            // QK^T (swapped): sf[mi][nf] holds S[kv=nf*16+lg*4+i][q=mi*16+lr]
            f32x4 sf[2][4] = {};
#pragma unroll
            for (int kk = 0; kk < 4; ++kk)
#pragma unroll
                for (int nf = 0; nf < 4; ++nf) {
                    bf16x8 kf = *(const bf16x8*)(
                        &Ks[cur][(nf * 16 + lr) * 128 + ((kk * 4 + lg) ^ e) * 8]);
#pragma unroll
                    for (int mi = 0; mi < 2; ++mi)
                        sf[mi][nf] = __builtin_amdgcn_mfma_f32_16x16x32_bf16(
                            kf, qf[mi][kk], sf[mi][nf], 0, 0, 0);
                }

            // online softmax, lane-local per q-row (q = qmin + mi*16 + lr)
            float aO[2][4];
#pragma unroll
            for (int mi = 0; mi < 2; ++mi) {
                const int qrow = qmin + mi * 16 + lr;
                float mt = -1e30f;
#pragma unroll
                for (int nf = 0; nf < 4; ++nf)
#pragma unroll
                    for (int i = 0; i < 4; ++i) {
                        float sc = sf[mi][nf][i] * SCALE;
                        if (needMask && (t * 64 + nf * 16 + lg * 4 + i) > qrow)
                            sc = -1e30f;
                        sf[mi][nf][i] = sc;
                        mt = fmaxf(mt, sc);
                    }
                mt = fmaxf(mt, __shfl_xor(mt, 16));
                mt = fmaxf(mt, __shfl_xor(mt, 32));
                float mnew = fmaxf(mrow[mi], mt);
                float alpha = __expf(mrow[mi] - mnew);
                mrow[mi] = mnew;
                float rs = 0.f;
#pragma unroll
                for (int nf = 0; nf < 4; ++nf)
#pragma unroll
                    for (int i = 0; i < 4; ++i) {
                        float p = __expf(sf[mi][nf][i] - mnew);
                        sf[mi][nf][i] = p;
                        rs += p;
                    }
                rs += __shfl_xor(rs, 16);
                rs += __shfl_xor(rs, 32);
                lsum[mi] = lsum[mi] * alpha + rs;
#pragma unroll
                for (int i = 0; i < 4; ++i)
                    aO[mi][i] = __shfl(alpha, lg * 4 + i);
            }

            // rescale O accumulators
#pragma unroll
            for (int mi = 0; mi < 2; ++mi)
#pragma unroll
                for (int df = 0; df < 8; ++df)
#pragma unroll
                    for (int i = 0; i < 4; ++i)
                        oacc[mi][df][i] *= aO[mi][i];

            // pack P -> LDS (b64 writes, swizzled to match b128 reads)
#pragma unroll
            for (int mi = 0; mi < 2; ++mi)
#pragma unroll
                for (int nf = 0; nf < 4; ++nf) {
                    union { bf16_t bb[4]; uint2 u; } pk;
#pragma unroll
                    for (int i = 0; i < 4; ++i) pk.bb[i] = (bf16_t)sf[mi][nf][i];
                    int addr = (mi * 16 + lr) * 64 +
                               (((nf * 2 + (lg >> 1)) ^ e) << 3) + (lg & 1) * 4;
                    *(uint2*)(&Ps[w][addr]) = pk.u;
                }
            asm volatile("s_waitcnt lgkmcnt(0)" ::: "memory");
            __builtin_amdgcn_sched_barrier(0);

            // PV: O[q 32][d 128] += P[q 32][kv 64] * V^T[d][kv]
            bf16x8 pf[2][2];
#pragma unroll
            for (int mi = 0; mi < 2; ++mi)
#pragma unroll
                for (int k2 = 0; k2 < 2; ++k2)
                    pf[mi][k2] = *(const bf16x8*)(
                        &Ps[w][(mi * 16 + lr) * 64 + ((k2 * 4 + lg) ^ e) * 8]);
#pragma unroll
            for (int df = 0; df < 8; ++df)
#pragma unroll
                for (int k2 = 0; k2 < 2; ++k2) {
                    bf16x8 vf = *(const bf16x8*)(
                        &Vs[cur][(df * 16 + lr) * 64 + ((k2 * 4 + lg) ^ e) * 8]);
#pragma unroll
                    for (int mi = 0; mi < 2; ++mi)
                        oacc[mi][df] = __builtin_amdgcn_mfma_f32_16x16x32_bf16(
                            pf[mi][k2], vf, oacc[mi][df], 0, 0, 0);
                }
        }
        __syncthreads();   // drains vmcnt(0): next buffer staged + reads done
        cur ^= 1;
    }

    // epilogue: normalize + write Ob[b*SEQ+q][h*HD+d]
#pragma unroll
    for (int mi = 0; mi < 2; ++mi) {
        float ls[4];
#pragma unroll
        for (int i = 0; i < 4; ++i)
            ls[i] = 1.f / __shfl(lsum[mi], lg * 4 + i);
#pragma unroll
        for (int df = 0; df < 8; ++df)
#pragma unroll
            for (int i = 0; i < 4; ++i) {
                float o = oacc[mi][df][i] * ls[i];
                int gm = b * SEQ + qmin + mi * 16 + lg * 4 + i;
                int gn = h * HD + df * 16 + lr;
                Ob[(size_t)gm * DIM + gn] = (bf16_t)o;
            }
    }
}

// ---------------- launcher ----------------
extern "C" void kernel_launch(void* const* d_in, const int* in_sizes, int n_in,
                              void* d_out, int out_size, void* d_ws, size_t ws_size,
                              hipStream_t stream) {
    const float* x    = (const float*)d_in[0];
    const float* cosT = (const float*)d_in[1];
    const float* sinT = (const float*)d_in[2];
    const float* wq   = (const float*)d_in[3];
    const float* wk   = (const float*)d_in[4];
    const float* wv   = (const float*)d_in[5];
    const float* wo   = (const float*)d_in[6];

    bf16_t* p = (bf16_t*)d_ws;
    bf16_t* xb  = p; p += (size_t)MTOT * DIM;
    bf16_t* wqb = p; p += (size_t)DIM * DIM;
    bf16_t* wkb = p; p += (size_t)NKVH * HD * DIM;
    bf16_t* wvb = p; p += (size_t)NKVH * HD * DIM;
    bf16_t* wob = p; p += (size_t)DIM * DIM;
    bf16_t* Qr  = p; p += (size_t)MTOT * DIM;
    bf16_t* Kr  = p; p += (size_t)BATCH * NKVH * SEQ * HD;
    bf16_t* Vt  = p; p += (size_t)BATCH * NKVH * HD * SEQ;
    bf16_t* Ob  = p; p += (size_t)MTOT * DIM;

    cvt_f32_bf16<<<1024, 256, 0, stream>>>(x,  xb,  MTOT * DIM / 4);
    cvt_f32_bf16<<<1024, 256, 0, stream>>>(wq, wqb, DIM * DIM / 4);
    cvt_f32_bf16<<<512,  256, 0, stream>>>(wk, wkb, NKVH * HD * DIM / 4);
    cvt_f32_bf16<<<512,  256, 0, stream>>>(wv, wvb, NKVH * HD * DIM / 4);
    cvt_f32_bf16<<<1024, 256, 0, stream>>>(wo, wob, DIM * DIM / 4);

    gemm_bt<1><<<dim3(MTOT / 128, DIM / 128), 256, 0, stream>>>(
        xb, wqb, nullptr, DIM, nullptr, Qr, nullptr, cosT, sinT);
    gemm_bt<2><<<dim3(MTOT / 128, 16), 256, 0, stream>>>(
        xb, wkb, wvb, DIM, nullptr, Kr, Vt, cosT, sinT);

    attn_fwd<<<1024, 256, 0, stream>>>(Qr, Kr, Vt, Ob);

    gemm_bt<0><<<dim3(MTOT / 128, DIM / 128), 256, 0, stream>>>(
        Ob, wob, nullptr, DIM, (float*)d_out, nullptr, nullptr, nullptr, nullptr);
}

// Round 3
// 593.323 us; speedup vs baseline: 1.8689x; 1.1505x over previous
//
#include <hip/hip_runtime.h>
#include <hip/hip_bf16.h>
#include <stdint.h>

#define DIM    4096
#define NH     32
#define NKVH   8
#define HD     128
#define SEQ    2048
#define BATCH  2
#define MTOT   (BATCH*SEQ)      // 4096
#define SCALE  0.08838834764831845f

typedef __bf16 bf16_t;
typedef __bf16 bf16x8 __attribute__((ext_vector_type(8)));
typedef float  f32x4  __attribute__((ext_vector_type(4)));

#define AS1 __attribute__((address_space(1)))
#define AS3 __attribute__((address_space(3)))

__device__ __forceinline__ void gload_lds16(const void* g, void* l) {
    __builtin_amdgcn_global_load_lds((const AS1 void*)g, (AS3 void*)l, 16, 0, 0);
}

__device__ __forceinline__ void fence_barrier() {
    asm volatile("" ::: "memory");
    __builtin_amdgcn_s_barrier();
    asm volatile("" ::: "memory");
}

// ---------------- f32 -> bf16 convert (vectorized) ----------------
__global__ __launch_bounds__(256)
void cvt_f32_bf16(const float* __restrict__ in, bf16_t* __restrict__ out, int n4) {
    for (int i = blockIdx.x * blockDim.x + threadIdx.x; i < n4;
         i += gridDim.x * blockDim.x) {
        float4 v = reinterpret_cast<const float4*>(in)[i];
        union { bf16_t b[4]; uint2 u; } t;
        t.b[0] = (bf16_t)v.x; t.b[1] = (bf16_t)v.y;
        t.b[2] = (bf16_t)v.z; t.b[3] = (bf16_t)v.w;
        reinterpret_cast<uint2*>(out)[i] = t.u;
    }
}

// ============ 256x256-tile 8-wave GEMM, 4-phase K-loop, counted vmcnt ======
// out[m][n] = sum_k A[m][k] * W[n][k], K = DIM = 4096, BK = 64.
// 512 threads = 8 waves (2 wm x 4 wn); wave tile 128x64 = 8x4 frags.
// LDS: A/B double-buffered, 2 halves each (128 rows x 64 k), 128 KiB total.
// Swizzle: 16B-chunk index c stored at c^(row&7) (pre-swizzled global src,
// linear gload_lds dest, XOR on ds_read) -> conflict-free b128 reads.
// Schedule per K-tile j (buf = j&1):
//  P0: read A-kk0(8)+B-kk0(4); stage A(j+1)h0 -> buf^1; bar; MFMA kk0,ni01; bar
//  P1: read B-kk1(4);          stage A(j+1)h1 -> buf^1; bar; MFMA kk0,ni23;
//      lgkmcnt(0); bar                      (drains all B(j) reads -> P2 safe)
//  P2: read A-kk1(8);          stage B(j+2)h0 -> buf;   bar; MFMA kk1,ni01; bar
//  P3:                          stage B(j+2)h1 -> buf;  bar; MFMA kk1,ni23;
//      vmcnt(4); bar      (A(j+1)+B(j+1) landed; B(j+2)'s 4 loads in flight)

__device__ __forceinline__ void stage_half(const bf16_t* gbase, int kt, int h,
                                           bf16_t* ldsdst, int tid, int w) {
#pragma unroll
    for (int t2 = 0; t2 < 2; ++t2) {
        int s = t2 * 512 + tid;
        int r = s >> 3, c = s & 7;
        gload_lds16(gbase + (size_t)(h * 128 + r) * DIM + kt + ((c ^ (r & 7)) * 8),
                    ldsdst + (size_t)(t2 * 512 + w * 64) * 8);
    }
}

__device__ __forceinline__ void read_a8(bf16x8* a, const bf16_t* Ahalf,
                                        int kk, int lr, int lg) {
#pragma unroll
    for (int mi = 0; mi < 8; ++mi) {
        int r = mi * 16 + lr;
        a[mi] = *(const bf16x8*)(Ahalf + r * 64 + ((kk * 4 + lg) ^ (r & 7)) * 8);
    }
}

__device__ __forceinline__ void read_b4(bf16x8* b, const bf16_t* Bhalf,
                                        int kk, int rb, int lg) {
#pragma unroll
    for (int ni = 0; ni < 4; ++ni) {
        int r = rb + ni * 16;
        b[ni] = *(const bf16x8*)(Bhalf + r * 64 + ((kk * 4 + lg) ^ (r & 7)) * 8);
    }
}

template<int MODE>
__global__ __launch_bounds__(512, 2)
void gemm8(const bf16_t* __restrict__ A,
           const bf16_t* __restrict__ B0,
           const bf16_t* __restrict__ B1,
           float* __restrict__ outF,
           bf16_t* __restrict__ outQ,
           bf16_t* __restrict__ outV,
           const float* __restrict__ cosT,
           const float* __restrict__ sinT) {
    __shared__ __align__(16) bf16_t As[2][2][128 * 64];
    __shared__ __align__(16) bf16_t Bs[2][2][128 * 64];

    const int tid = threadIdx.x;
    const int l = tid & 63;
    const int w = tid >> 6;           // 0..7
    const int wm = w >> 2, wn = w & 3;
    const int lr = l & 15, lg = l >> 4;
    const int rb = (wn & 1) * 64 + lr;

    const int rowBase = blockIdx.x * 256;
    const int ct = blockIdx.y;

    const bf16_t* Ap = A + (size_t)rowBase * DIM;
    const bf16_t* Bp;
    if (MODE == 2) Bp = (ct < 4) ? (B0 + (size_t)ct * 256 * DIM)
                                 : (B1 + (size_t)(ct - 4) * 256 * DIM);
    else           Bp = B0 + (size_t)ct * 256 * DIM;

    f32x4 acc[8][4] = {};
    bf16x8 a0[8], a1[8], b0[4], b1[4];

    // ---- prologue: B(0), A(0), B(1) = 12 loads; keep B(1)'s 4 in flight ----
    stage_half(Bp, 0,  0, &Bs[0][0][0], tid, w);
    stage_half(Bp, 0,  1, &Bs[0][1][0], tid, w);
    stage_half(Ap, 0,  0, &As[0][0][0], tid, w);
    stage_half(Ap, 0,  1, &As[0][1][0], tid, w);
    stage_half(Bp, 64, 0, &Bs[1][0][0], tid, w);
    stage_half(Bp, 64, 1, &Bs[1][1][0], tid, w);
    asm volatile("s_waitcnt vmcnt(4)" ::: "memory");
    fence_barrier();

    const int NT = DIM / 64;   // 64
    for (int j = 0; j < NT; ++j) {
        const int buf = j & 1;
        const int ktA = (j + 1 < NT ? j + 1 : NT - 1) * 64;
        const int ktB = (j + 2 < NT ? j + 2 : NT - 1) * 64;
        const bf16_t* Ahalf = &As[buf][wm][0];
        const bf16_t* Bhalf = &Bs[buf][wn >> 1][0];

        // ---------- P0 ----------
        read_a8(a0, Ahalf, 0, lr, lg);
        read_b4(b0, Bhalf, 0, rb, lg);
        stage_half(Ap, ktA, 0, &As[buf ^ 1][0][0], tid, w);
        fence_barrier();
        __builtin_amdgcn_s_setprio(1);
#pragma unroll
        for (int mi = 0; mi < 8; ++mi) {
            acc[mi][0] = __builtin_amdgcn_mfma_f32_16x16x32_bf16(a0[mi], b0[0], acc[mi][0], 0, 0, 0);
            acc[mi][1] = __builtin_amdgcn_mfma_f32_16x16x32_bf16(a0[mi], b0[1], acc[mi][1], 0, 0, 0);
        }
        __builtin_amdgcn_s_setprio(0);
        __builtin_amdgcn_sched_barrier(0);
        fence_barrier();

        // ---------- P1 ----------
        read_b4(b1, Bhalf, 1, rb, lg);
        stage_half(Ap, ktA, 1, &As[buf ^ 1][1][0], tid, w);
        fence_barrier();
        __builtin_amdgcn_s_setprio(1);
#pragma unroll
        for (int mi = 0; mi < 8; ++mi) {
            acc[mi][2] = __builtin_amdgcn_mfma_f32_16x16x32_bf16(a0[mi], b0[2], acc[mi][2], 0, 0, 0);
            acc[mi][3] = __builtin_amdgcn_mfma_f32_16x16x32_bf16(a0[mi], b0[3], acc[mi][3], 0, 0, 0);
        }
        __builtin_amdgcn_s_setprio(0);
        __builtin_amdgcn_sched_barrier(0);
        asm volatile("s_waitcnt lgkmcnt(0)" ::: "memory");  // drain all B(j) reads
        fence_barrier();

        // ---------- P2 ----------  (B(j) slots now safe to overwrite)
        read_a8(a1, Ahalf, 1, lr, lg);
        stage_half(Bp, ktB, 0, &Bs[buf][0][0], tid, w);
        fence_barrier();
        __builtin_amdgcn_s_setprio(1);
#pragma unroll
        for (int mi = 0; mi < 8; ++mi) {
            acc[mi][0] = __builtin_amdgcn_mfma_f32_16x16x32_bf16(a1[mi], b1[0], acc[mi][0], 0, 0, 0);
            acc[mi][1] = __builtin_amdgcn_mfma_f32_16x16x32_bf16(a1[mi], b1[1], acc[mi][1], 0, 0, 0);
        }
        __builtin_amdgcn_s_setprio(0);
        __builtin_amdgcn_sched_barrier(0);
        fence_barrier();

        // ---------- P3 ----------
        stage_half(Bp, ktB, 1, &Bs[buf][1][0], tid, w);
        fence_barrier();
        __builtin_amdgcn_s_setprio(1);
#pragma unroll
        for (int mi = 0; mi < 8; ++mi) {
            acc[mi][2] = __builtin_amdgcn_mfma_f32_16x16x32_bf16(a1[mi], b1[2], acc[mi][2], 0, 0, 0);
            acc[mi][3] = __builtin_amdgcn_mfma_f32_16x16x32_bf16(a1[mi], b1[3], acc[mi][3], 0, 0, 0);
        }
        __builtin_amdgcn_s_setprio(0);
        __builtin_amdgcn_sched_barrier(0);
        asm volatile("s_waitcnt vmcnt(4)" ::: "memory");    // next tile fully landed
        fence_barrier();
    }

    // ---- epilogue ----
#pragma unroll
    for (int mi = 0; mi < 8; ++mi) {
        int gmBase = rowBase + wm * 128 + mi * 16 + lg * 4;
#pragma unroll
        for (int ni = 0; ni < 4; ++ni) {
            f32x4 v4 = acc[mi][ni];
            int gn = ct * 256 + wn * 64 + ni * 16 + lr;
            if (MODE == 0) {
#pragma unroll
                for (int i = 0; i < 4; ++i)
                    outF[(size_t)(gmBase + i) * DIM + gn] = v4[i];
            } else if (MODE == 1) {
                int h = gn >> 7, d = gn & 127, pi2 = d >> 1;
#pragma unroll
                for (int i = 0; i < 4; ++i) {
                    float v = v4[i];
                    float pvv = __shfl_xor(v, 1);
                    int gm = gmBase + i;
                    int bb = gm >> 11, sidx = gm & (SEQ - 1);
                    float c = cosT[sidx * 64 + pi2], sn = sinT[sidx * 64 + pi2];
                    float o = (d & 1) ? (pvv * sn + v * c) : (v * c - pvv * sn);
                    outQ[((size_t)(bb * NH + h) * SEQ + sidx) * HD + d] = (bf16_t)o;
                }
            } else { // MODE 2
                if (ct < 4) { // K path: gn in [0,1024)
                    int h = gn >> 7, d = gn & 127, pi2 = d >> 1;
#pragma unroll
                    for (int i = 0; i < 4; ++i) {
                        float v = v4[i];
                        float pvv = __shfl_xor(v, 1);
                        int gm = gmBase + i;
                        int bb = gm >> 11, sidx = gm & (SEQ - 1);
                        float c = cosT[sidx * 64 + pi2], sn = sinT[sidx * 64 + pi2];
                        float o = (d & 1) ? (pvv * sn + v * c) : (v * c - pvv * sn);
                        outQ[((size_t)(bb * NKVH + h) * SEQ + sidx) * HD + d] = (bf16_t)o;
                    }
                } else {      // V path
                    int gnv = (ct - 4) * 256 + wn * 64 + ni * 16 + lr;
                    int kvh = gnv >> 7, d = gnv & 127;
#pragma unroll
                    for (int i = 0; i < 4; ++i) {
                        float dummy = __shfl_xor(v4[i], 1); (void)dummy;
                        int gm = gmBase + i;
                        int bb = gm >> 11, sidx = gm & (SEQ - 1);
                        outV[((size_t)(bb * NKVH + kvh) * HD + d) * SEQ + sidx] = (bf16_t)v4[i];
                    }
                }
            }
        }
    }
}

// ---------------- flash attention (causal, GQA) ---------------- (unchanged)
__global__ __launch_bounds__(256, 2)
void attn_fwd(const bf16_t* __restrict__ Qr,
              const bf16_t* __restrict__ Kr,
              const bf16_t* __restrict__ Vt,
              bf16_t* __restrict__ Ob) {
    __shared__ __align__(16) bf16_t Ks[2][64 * 128];   // [kv][d], swizzled
    __shared__ __align__(16) bf16_t Vs[2][128 * 64];   // [d][kv], swizzled
    __shared__ __align__(16) bf16_t Ps[4][32 * 64];    // per-wave P, swizzled

    const int tid = threadIdx.x;
    const int l  = tid & 63;
    const int w  = tid >> 6;
    const int lr = l & 15, lg = l >> 4;
    const int e  = lr & 7;

    const int qt  = 15 - (blockIdx.x >> 6);
    const int bh  = blockIdx.x & 63;
    const int b   = bh >> 5;
    const int h   = bh & 31;
    const int kvh = h >> 2;
    const int q0  = qt * 128;
    const int nt  = 2 * qt + 2;
    const int qmin = q0 + w * 32;

    const bf16_t* kbase = Kr + (size_t)(b * NKVH + kvh) * SEQ * HD;
    const bf16_t* vbase = Vt + (size_t)(b * NKVH + kvh) * HD * SEQ;

    bf16x8 qf[2][4];
    const bf16_t* qp = Qr + ((size_t)(b * NH + h) * SEQ + qmin + lr) * HD;
#pragma unroll
    for (int mi = 0; mi < 2; ++mi)
#pragma unroll
        for (int kk = 0; kk < 4; ++kk)
            qf[mi][kk] = *(const bf16x8*)(qp + (size_t)mi * 16 * HD + kk * 32 + lg * 8);

    f32x4 oacc[2][8] = {};
    float mrow[2] = {-1e30f, -1e30f};
    float lsum[2] = {0.f, 0.f};

#pragma unroll
    for (int t2 = 0; t2 < 4; ++t2) {
        int s = t2 * 256 + tid;
        { int r = s >> 4, g = (s & 15) ^ (r & 7);
          gload_lds16(kbase + (size_t)r * HD + g * 8,
                      &Ks[0][(size_t)(t2 * 256 + w * 64) * 8]); }
        { int r = s >> 3, g = (s & 7) ^ (r & 7);
          gload_lds16(vbase + (size_t)r * SEQ + g * 8,
                      &Vs[0][(size_t)(t2 * 256 + w * 64) * 8]); }
    }
    __syncthreads();

    int cur = 0;
    for (int t = 0; t < nt; ++t) {
        if (t + 1 < nt) {
            const int kv1 = (t + 1) * 64;
#pragma unroll
            for (int t2 = 0; t2 < 4; ++t2) {
                int s = t2 * 256 + tid;
                { int r = s >> 4, g = (s & 15) ^ (r & 7);
                  gload_lds16(kbase + (size_t)(kv1 + r) * HD + g * 8,
                              &Ks[cur ^ 1][(size_t)(t2 * 256 + w * 64) * 8]); }
                { int r = s >> 3, g = (s & 7) ^ (r & 7);
                  gload_lds16(vbase + (size_t)r * SEQ + kv1 + g * 8,
                              &Vs[cur ^ 1][(size_t)(t2 * 256 + w * 64) * 8]); }
            }
        }

        const bool active = (t * 64) <= (qmin + 31);
        if (active) {
            const bool needMask = (t * 64 + 63) > qmin;

            f32x4 sf[2][4] = {};
#pragma unroll
            for (int kk = 0; kk < 4; ++kk)
#pragma unroll
                for (int nf = 0; nf < 4; ++nf) {
                    bf16x8 kf = *(const bf16x8*)(
                        &Ks[cur][(nf * 16 + lr) * 128 + ((kk * 4 + lg) ^ e) * 8]);
#pragma unroll
                    for (int mi = 0; mi < 2; ++mi)
                        sf[mi][nf] = __builtin_amdgcn_mfma_f32_16x16x32_bf16(
                            kf, qf[mi][kk], sf[mi][nf], 0, 0, 0);
                }

            float aO[2][4];
#pragma unroll
            for (int mi = 0; mi < 2; ++mi) {
                const int qrow = qmin + mi * 16 + lr;
                float mt = -1e30f;
#pragma unroll
                for (int nf = 0; nf < 4; ++nf)
#pragma unroll
                    for (int i = 0; i < 4; ++i) {
                        float sc = sf[mi][nf][i] * SCALE;
                        if (needMask && (t * 64 + nf * 16 + lg * 4 + i) > qrow)
                            sc = -1e30f;
                        sf[mi][nf][i] = sc;
                        mt = fmaxf(mt, sc);
                    }
                mt = fmaxf(mt, __shfl_xor(mt, 16));
                mt = fmaxf(mt, __shfl_xor(mt, 32));
                float mnew = fmaxf(mrow[mi], mt);
                float alpha = __expf(mrow[mi] - mnew);
                mrow[mi] = mnew;
                float rs = 0.f;
#pragma unroll
                for (int nf = 0; nf < 4; ++nf)
#pragma unroll
                    for (int i = 0; i < 4; ++i) {
                        float p = __expf(sf[mi][nf][i] - mnew);
                        sf[mi][nf][i] = p;
                        rs += p;
                    }
                rs += __shfl_xor(rs, 16);
                rs += __shfl_xor(rs, 32);
                lsum[mi] = lsum[mi] * alpha + rs;
#pragma unroll
                for (int i = 0; i < 4; ++i)
                    aO[mi][i] = __shfl(alpha, lg * 4 + i);
            }

#pragma unroll
            for (int mi = 0; mi < 2; ++mi)
#pragma unroll
                for (int df = 0; df < 8; ++df)
#pragma unroll
                    for (int i = 0; i < 4; ++i)
                        oacc[mi][df][i] *= aO[mi][i];

#pragma unroll
            for (int mi = 0; mi < 2; ++mi)
#pragma unroll
                for (int nf = 0; nf < 4; ++nf) {
                    union { bf16_t bb[4]; uint2 u; } pk;
#pragma unroll
                    for (int i = 0; i < 4; ++i) pk.bb[i] = (bf16_t)sf[mi][nf][i];
                    int addr = (mi * 16 + lr) * 64 +
                               (((nf * 2 + (lg >> 1)) ^ e) << 3) + (lg & 1) * 4;
                    *(uint2*)(&Ps[w][addr]) = pk.u;
                }
            asm volatile("s_waitcnt lgkmcnt(0)" ::: "memory");
            __builtin_amdgcn_sched_barrier(0);

            bf16x8 pf[2][2];
#pragma unroll
            for (int mi = 0; mi < 2; ++mi)
#pragma unroll
                for (int k2 = 0; k2 < 2; ++k2)
                    pf[mi][k2] = *(const bf16x8*)(
                        &Ps[w][(mi * 16 + lr) * 64 + ((k2 * 4 + lg) ^ e) * 8]);
#pragma unroll
            for (int df = 0; df < 8; ++df)
#pragma unroll
                for (int k2 = 0; k2 < 2; ++k2) {
                    bf16x8 vf = *(const bf16x8*)(
                        &Vs[cur][(df * 16 + lr) * 64 + ((k2 * 4 + lg) ^ e) * 8]);
#pragma unroll
                    for (int mi = 0; mi < 2; ++mi)
                        oacc[mi][df] = __builtin_amdgcn_mfma_f32_16x16x32_bf16(
                            pf[mi][k2], vf, oacc[mi][df], 0, 0, 0);
                }
        }
        __syncthreads();
        cur ^= 1;
    }

#pragma unroll
    for (int mi = 0; mi < 2; ++mi) {
        float ls[4];
#pragma unroll
        for (int i = 0; i < 4; ++i)
            ls[i] = 1.f / __shfl(lsum[mi], lg * 4 + i);
#pragma unroll
        for (int df = 0; df < 8; ++df)
#pragma unroll
            for (int i = 0; i < 4; ++i) {
                float o = oacc[mi][df][i] * ls[i];
                int gm = b * SEQ + qmin + mi * 16 + lg * 4 + i;
                int gn = h * HD + df * 16 + lr;
                Ob[(size_t)gm * DIM + gn] = (bf16_t)o;
            }
    }
}

// ---------------- launcher ----------------
extern "C" void kernel_launch(void* const* d_in, const int* in_sizes, int n_in,
                              void* d_out, int out_size, void* d_ws, size_t ws_size,
                              hipStream_t stream) {
    const float* x    = (const float*)d_in[0];
    const float* cosT = (const float*)d_in[1];
    const float* sinT = (const float*)d_in[2];
    const float* wq   = (const float*)d_in[3];
    const float* wk   = (const float*)d_in[4];
    const float* wv   = (const float*)d_in[5];
    const float* wo   = (const float*)d_in[6];

    bf16_t* p = (bf16_t*)d_ws;
    bf16_t* xb  = p; p += (size_t)MTOT * DIM;
    bf16_t* wqb = p; p += (size_t)DIM * DIM;
    bf16_t* wkb = p; p += (size_t)NKVH * HD * DIM;
    bf16_t* wvb = p; p += (size_t)NKVH * HD * DIM;
    bf16_t* wob = p; p += (size_t)DIM * DIM;
    bf16_t* Qr  = p; p += (size_t)MTOT * DIM;
    bf16_t* Kr  = p; p += (size_t)BATCH * NKVH * SEQ * HD;
    bf16_t* Vt  = p; p += (size_t)BATCH * NKVH * HD * SEQ;
    bf16_t* Ob  = p; p += (size_t)MTOT * DIM;

    cvt_f32_bf16<<<1024, 256, 0, stream>>>(x,  xb,  MTOT * DIM / 4);
    cvt_f32_bf16<<<1024, 256, 0, stream>>>(wq, wqb, DIM * DIM / 4);
    cvt_f32_bf16<<<512,  256, 0, stream>>>(wk, wkb, NKVH * HD * DIM / 4);
    cvt_f32_bf16<<<512,  256, 0, stream>>>(wv, wvb, NKVH * HD * DIM / 4);
    cvt_f32_bf16<<<1024, 256, 0, stream>>>(wo, wob, DIM * DIM / 4);

    gemm8<1><<<dim3(16, 16), 512, 0, stream>>>(
        xb, wqb, nullptr, nullptr, Qr, nullptr, cosT, sinT);
    gemm8<2><<<dim3(16, 8), 512, 0, stream>>>(
        xb, wkb, wvb, nullptr, Kr, Vt, cosT, sinT);

    attn_fwd<<<1024, 256, 0, stream>>>(Qr, Kr, Vt, Ob);

    gemm8<0><<<dim3(16, 16), 512, 0, stream>>>(
        Ob, wob, nullptr, (float*)d_out, nullptr, nullptr, nullptr, nullptr);
}

// Round 4
// 520.051 us; speedup vs baseline: 2.1322x; 1.1409x over previous
//
#include <hip/hip_runtime.h>
#include <hip/hip_bf16.h>
#include <stdint.h>

#define DIM    4096
#define NH     32
#define NKVH   8
#define HD     128
#define SEQ    2048
#define BATCH  2
#define MTOT   (BATCH*SEQ)      // 4096
#define SCALE  0.08838834764831845f

typedef __bf16 bf16_t;
typedef __bf16 bf16x8 __attribute__((ext_vector_type(8)));
typedef float  f32x4  __attribute__((ext_vector_type(4)));

#define AS1 __attribute__((address_space(1)))
#define AS3 __attribute__((address_space(3)))

__device__ __forceinline__ void gload_lds16(const void* g, void* l) {
    __builtin_amdgcn_global_load_lds((const AS1 void*)g, (AS3 void*)l, 16, 0, 0);
}

__device__ __forceinline__ void fence_barrier() {
    asm volatile("" ::: "memory");
    __builtin_amdgcn_s_barrier();
    asm volatile("" ::: "memory");
}

// ---------------- f32 -> bf16 converts ----------------
__global__ __launch_bounds__(256)
void cvt_f32_bf16(const float* __restrict__ in, bf16_t* __restrict__ out, int n4) {
    for (int i = blockIdx.x * blockDim.x + threadIdx.x; i < n4;
         i += gridDim.x * blockDim.x) {
        float4 v = reinterpret_cast<const float4*>(in)[i];
        union { bf16_t b[4]; uint2 u; } t;
        t.b[0] = (bf16_t)v.x; t.b[1] = (bf16_t)v.y;
        t.b[2] = (bf16_t)v.z; t.b[3] = (bf16_t)v.w;
        reinterpret_cast<uint2*>(out)[i] = t.u;
    }
}

// fused convert of wq|wk|wv|wo into one contiguous bf16 region
// region sizes (in float4): 4M | 1M | 1M | 4M
__global__ __launch_bounds__(256)
void cvt_weights(const float* __restrict__ wq, const float* __restrict__ wk,
                 const float* __restrict__ wv, const float* __restrict__ wo,
                 bf16_t* __restrict__ out) {
    const int n0 = DIM * DIM / 4;            // wq
    const int n1 = NKVH * HD * DIM / 4;      // wk
    const int n2 = NKVH * HD * DIM / 4;      // wv
    const int n3 = DIM * DIM / 4;            // wo
    const int ntot = n0 + n1 + n2 + n3;
    for (int i = blockIdx.x * blockDim.x + threadIdx.x; i < ntot;
         i += gridDim.x * blockDim.x) {
        const float* src;
        int k = i;
        if (k < n0) src = wq;
        else if ((k -= n0) < n1) src = wk;
        else if ((k -= n1) < n2) src = wv;
        else { k -= n2; src = wo; }
        float4 v = reinterpret_cast<const float4*>(src)[k];
        union { bf16_t b[4]; uint2 u; } t;
        t.b[0] = (bf16_t)v.x; t.b[1] = (bf16_t)v.y;
        t.b[2] = (bf16_t)v.z; t.b[3] = (bf16_t)v.w;
        reinterpret_cast<uint2*>(out)[i] = t.u;
    }
}

// ============ 256x256-tile 8-wave GEMM, reg-pipelined 2-region K-loop ======
// out[m][n] = sum_k A[m][k] * W[n][k], K = DIM = 4096, BK = 64.
// 512 threads = 8 waves (2 wm x 4 wn); wave tile 128x64 = 8x4 frags.
// LDS: A/B double-buffered (tile j in slot j&1), 128 KiB total.
// Register pipeline: operands for each 32-MFMA cluster are ds_read one
// cluster AHEAD, so MFMA never waits on same-region reads:
//  Region A(j): issue R1(j)=a1,b1 (12 b128) ; MFMA kk0(j) (a0,b0 ready);
//               lgkm(0); bar     (all tile-j reads drained -> overwrites ok)
//  Region B(j): issue S(j+2) stage (8 gload_lds, into slot j&1);
//               MFMA kk1(j); vmcnt(8) (S(j+1) landed, S(j+2) in flight);
//               bar; issue R0(j+1)=a0,b0 from slot (j+1)&1.

__device__ __forceinline__ void stage_half(const bf16_t* gbase, int kt, int h,
                                           bf16_t* ldsdst, int tid, int w) {
#pragma unroll
    for (int t2 = 0; t2 < 2; ++t2) {
        int s = t2 * 512 + tid;
        int r = s >> 3, c = s & 7;
        gload_lds16(gbase + (size_t)(h * 128 + r) * DIM + kt + ((c ^ (r & 7)) * 8),
                    ldsdst + (size_t)(t2 * 512 + w * 64) * 8);
    }
}

__device__ __forceinline__ void read_a8(bf16x8* a, const bf16_t* Ahalf,
                                        int kk, int lr, int lg) {
#pragma unroll
    for (int mi = 0; mi < 8; ++mi) {
        int r = mi * 16 + lr;
        a[mi] = *(const bf16x8*)(Ahalf + r * 64 + ((kk * 4 + lg) ^ (r & 7)) * 8);
    }
}

__device__ __forceinline__ void read_b4(bf16x8* b, const bf16_t* Bhalf,
                                        int kk, int rb, int lg) {
#pragma unroll
    for (int ni = 0; ni < 4; ++ni) {
        int r = rb + ni * 16;
        b[ni] = *(const bf16x8*)(Bhalf + r * 64 + ((kk * 4 + lg) ^ (r & 7)) * 8);
    }
}

template<int MODE>
__global__ __launch_bounds__(512, 2)
void gemm8(const bf16_t* __restrict__ A,
           const bf16_t* __restrict__ B0,
           const bf16_t* __restrict__ B1,
           float* __restrict__ outF,
           bf16_t* __restrict__ outQ,
           bf16_t* __restrict__ outV,
           const float* __restrict__ cosT,
           const float* __restrict__ sinT) {
    __shared__ __align__(16) bf16_t As[2][2][128 * 64];
    __shared__ __align__(16) bf16_t Bs[2][2][128 * 64];

    const int tid = threadIdx.x;
    const int l = tid & 63;
    const int w = tid >> 6;           // 0..7
    const int wm = w >> 2, wn = w & 3;
    const int lr = l & 15, lg = l >> 4;
    const int rb = (wn & 1) * 64 + lr;
    const int bh2 = wn >> 1;

    const int rowBase = blockIdx.x * 256;
    const int ct = blockIdx.y;

    const bf16_t* Ap = A + (size_t)rowBase * DIM;
    const bf16_t* Bp;
    if (MODE == 2) Bp = (ct < 4) ? (B0 + (size_t)ct * 256 * DIM)
                                 : (B1 + (size_t)(ct - 4) * 256 * DIM);
    else           Bp = B0 + (size_t)ct * 256 * DIM;

    f32x4 acc[8][4] = {};
    bf16x8 a0[8], a1[8], b0[4], b1[4];

    const int NT = DIM / 64;   // 64

    // ---- prologue: stage tiles 0 and 1; gate tile 0; pre-read R0(0) ----
    stage_half(Ap, 0,  0, &As[0][0][0], tid, w);
    stage_half(Ap, 0,  1, &As[0][1][0], tid, w);
    stage_half(Bp, 0,  0, &Bs[0][0][0], tid, w);
    stage_half(Bp, 0,  1, &Bs[0][1][0], tid, w);
    stage_half(Ap, 64, 0, &As[1][0][0], tid, w);
    stage_half(Ap, 64, 1, &As[1][1][0], tid, w);
    stage_half(Bp, 64, 0, &Bs[1][0][0], tid, w);
    stage_half(Bp, 64, 1, &Bs[1][1][0], tid, w);
    asm volatile("s_waitcnt vmcnt(8)" ::: "memory");   // tile 0 landed
    fence_barrier();
    read_a8(a0, &As[0][wm][0], 0, lr, lg);
    read_b4(b0, &Bs[0][bh2][0], 0, rb, lg);

    for (int j = 0; j < NT; ++j) {
        const int buf = j & 1;

        // ---------- Region A ----------
        read_a8(a1, &As[buf][wm][0], 1, lr, lg);
        read_b4(b1, &Bs[buf][bh2][0], 1, rb, lg);
        __builtin_amdgcn_s_setprio(1);
#pragma unroll
        for (int mi = 0; mi < 8; ++mi) {
            acc[mi][0] = __builtin_amdgcn_mfma_f32_16x16x32_bf16(a0[mi], b0[0], acc[mi][0], 0, 0, 0);
            acc[mi][1] = __builtin_amdgcn_mfma_f32_16x16x32_bf16(a0[mi], b0[1], acc[mi][1], 0, 0, 0);
            acc[mi][2] = __builtin_amdgcn_mfma_f32_16x16x32_bf16(a0[mi], b0[2], acc[mi][2], 0, 0, 0);
            acc[mi][3] = __builtin_amdgcn_mfma_f32_16x16x32_bf16(a0[mi], b0[3], acc[mi][3], 0, 0, 0);
        }
        __builtin_amdgcn_s_setprio(0);
        asm volatile("s_waitcnt lgkmcnt(0)" ::: "memory");  // all tile-j reads drained
        fence_barrier();

        // ---------- Region B ----------
        {   // stage tile j+2 into slot (j+2)&1 == buf (clamped at tail:
            // duplicate stage of identical data is benign)
            const int t2i = (j + 2 < NT) ? (j + 2) : (NT - 1);
            const int kt2 = t2i * 64;
            bf16_t* Adst0 = &As[t2i & 1][0][0];
            bf16_t* Bdst0 = &Bs[t2i & 1][0][0];
            stage_half(Ap, kt2, 0, Adst0, tid, w);
            stage_half(Ap, kt2, 1, Adst0 + 128 * 64, tid, w);
            stage_half(Bp, kt2, 0, Bdst0, tid, w);
            stage_half(Bp, kt2, 1, Bdst0 + 128 * 64, tid, w);
        }
        __builtin_amdgcn_s_setprio(1);
#pragma unroll
        for (int mi = 0; mi < 8; ++mi) {
            acc[mi][0] = __builtin_amdgcn_mfma_f32_16x16x32_bf16(a1[mi], b1[0], acc[mi][0], 0, 0, 0);
            acc[mi][1] = __builtin_amdgcn_mfma_f32_16x16x32_bf16(a1[mi], b1[1], acc[mi][1], 0, 0, 0);
            acc[mi][2] = __builtin_amdgcn_mfma_f32_16x16x32_bf16(a1[mi], b1[2], acc[mi][2], 0, 0, 0);
            acc[mi][3] = __builtin_amdgcn_mfma_f32_16x16x32_bf16(a1[mi], b1[3], acc[mi][3], 0, 0, 0);
        }
        __builtin_amdgcn_s_setprio(0);
        asm volatile("s_waitcnt vmcnt(8)" ::: "memory");   // tile j+1 landed
        fence_barrier();
        if (j + 1 < NT) {
            read_a8(a0, &As[buf ^ 1][wm][0], 0, lr, lg);
            read_b4(b0, &Bs[buf ^ 1][bh2][0], 0, rb, lg);
        }
    }

    // ---- epilogue ----
#pragma unroll
    for (int mi = 0; mi < 8; ++mi) {
        int gmBase = rowBase + wm * 128 + mi * 16 + lg * 4;
#pragma unroll
        for (int ni = 0; ni < 4; ++ni) {
            f32x4 v4 = acc[mi][ni];
            int gn = ct * 256 + wn * 64 + ni * 16 + lr;
            if (MODE == 0) {
#pragma unroll
                for (int i = 0; i < 4; ++i)
                    outF[(size_t)(gmBase + i) * DIM + gn] = v4[i];
            } else if (MODE == 1) {
                int h = gn >> 7, d = gn & 127, pi2 = d >> 1;
#pragma unroll
                for (int i = 0; i < 4; ++i) {
                    float v = v4[i];
                    float pvv = __shfl_xor(v, 1);
                    int gm = gmBase + i;
                    int bb = gm >> 11, sidx = gm & (SEQ - 1);
                    float c = cosT[sidx * 64 + pi2], sn = sinT[sidx * 64 + pi2];
                    float o = (d & 1) ? (pvv * sn + v * c) : (v * c - pvv * sn);
                    outQ[((size_t)(bb * NH + h) * SEQ + sidx) * HD + d] = (bf16_t)o;
                }
            } else { // MODE 2
                if (ct < 4) { // K path: gn in [0,1024)
                    int h = gn >> 7, d = gn & 127, pi2 = d >> 1;
#pragma unroll
                    for (int i = 0; i < 4; ++i) {
                        float v = v4[i];
                        float pvv = __shfl_xor(v, 1);
                        int gm = gmBase + i;
                        int bb = gm >> 11, sidx = gm & (SEQ - 1);
                        float c = cosT[sidx * 64 + pi2], sn = sinT[sidx * 64 + pi2];
                        float o = (d & 1) ? (pvv * sn + v * c) : (v * c - pvv * sn);
                        outQ[((size_t)(bb * NKVH + h) * SEQ + sidx) * HD + d] = (bf16_t)o;
                    }
                } else {      // V path
                    int gnv = (ct - 4) * 256 + wn * 64 + ni * 16 + lr;
                    int kvh = gnv >> 7, d = gnv & 127;
#pragma unroll
                    for (int i = 0; i < 4; ++i) {
                        float dummy = __shfl_xor(v4[i], 1); (void)dummy;
                        int gm = gmBase + i;
                        int bb = gm >> 11, sidx = gm & (SEQ - 1);
                        outV[((size_t)(bb * NKVH + kvh) * HD + d) * SEQ + sidx] = (bf16_t)v4[i];
                    }
                }
            }
        }
    }
}

// ---------------- flash attention (causal, GQA) ---------------- (unchanged)
__global__ __launch_bounds__(256, 2)
void attn_fwd(const bf16_t* __restrict__ Qr,
              const bf16_t* __restrict__ Kr,
              const bf16_t* __restrict__ Vt,
              bf16_t* __restrict__ Ob) {
    __shared__ __align__(16) bf16_t Ks[2][64 * 128];   // [kv][d], swizzled
    __shared__ __align__(16) bf16_t Vs[2][128 * 64];   // [d][kv], swizzled
    __shared__ __align__(16) bf16_t Ps[4][32 * 64];    // per-wave P, swizzled

    const int tid = threadIdx.x;
    const int l  = tid & 63;
    const int w  = tid >> 6;
    const int lr = l & 15, lg = l >> 4;
    const int e  = lr & 7;

    const int qt  = 15 - (blockIdx.x >> 6);
    const int bh  = blockIdx.x & 63;
    const int b   = bh >> 5;
    const int h   = bh & 31;
    const int kvh = h >> 2;
    const int q0  = qt * 128;
    const int nt  = 2 * qt + 2;
    const int qmin = q0 + w * 32;

    const bf16_t* kbase = Kr + (size_t)(b * NKVH + kvh) * SEQ * HD;
    const bf16_t* vbase = Vt + (size_t)(b * NKVH + kvh) * HD * SEQ;

    bf16x8 qf[2][4];
    const bf16_t* qp = Qr + ((size_t)(b * NH + h) * SEQ + qmin + lr) * HD;
#pragma unroll
    for (int mi = 0; mi < 2; ++mi)
#pragma unroll
        for (int kk = 0; kk < 4; ++kk)
            qf[mi][kk] = *(const bf16x8*)(qp + (size_t)mi * 16 * HD + kk * 32 + lg * 8);

    f32x4 oacc[2][8] = {};
    float mrow[2] = {-1e30f, -1e30f};
    float lsum[2] = {0.f, 0.f};

#pragma unroll
    for (int t2 = 0; t2 < 4; ++t2) {
        int s = t2 * 256 + tid;
        { int r = s >> 4, g = (s & 15) ^ (r & 7);
          gload_lds16(kbase + (size_t)r * HD + g * 8,
                      &Ks[0][(size_t)(t2 * 256 + w * 64) * 8]); }
        { int r = s >> 3, g = (s & 7) ^ (r & 7);
          gload_lds16(vbase + (size_t)r * SEQ + g * 8,
                      &Vs[0][(size_t)(t2 * 256 + w * 64) * 8]); }
    }
    __syncthreads();

    int cur = 0;
    for (int t = 0; t < nt; ++t) {
        if (t + 1 < nt) {
            const int kv1 = (t + 1) * 64;
#pragma unroll
            for (int t2 = 0; t2 < 4; ++t2) {
                int s = t2 * 256 + tid;
                { int r = s >> 4, g = (s & 15) ^ (r & 7);
                  gload_lds16(kbase + (size_t)(kv1 + r) * HD + g * 8,
                              &Ks[cur ^ 1][(size_t)(t2 * 256 + w * 64) * 8]); }
                { int r = s >> 3, g = (s & 7) ^ (r & 7);
                  gload_lds16(vbase + (size_t)r * SEQ + kv1 + g * 8,
                              &Vs[cur ^ 1][(size_t)(t2 * 256 + w * 64) * 8]); }
            }
        }

        const bool active = (t * 64) <= (qmin + 31);
        if (active) {
            const bool needMask = (t * 64 + 63) > qmin;

            f32x4 sf[2][4] = {};
#pragma unroll
            for (int kk = 0; kk < 4; ++kk)
#pragma unroll
                for (int nf = 0; nf < 4; ++nf) {
                    bf16x8 kf = *(const bf16x8*)(
                        &Ks[cur][(nf * 16 + lr) * 128 + ((kk * 4 + lg) ^ e) * 8]);
#pragma unroll
                    for (int mi = 0; mi < 2; ++mi)
                        sf[mi][nf] = __builtin_amdgcn_mfma_f32_16x16x32_bf16(
                            kf, qf[mi][kk], sf[mi][nf], 0, 0, 0);
                }

            float aO[2][4];
#pragma unroll
            for (int mi = 0; mi < 2; ++mi) {
                const int qrow = qmin + mi * 16 + lr;
                float mt = -1e30f;
#pragma unroll
                for (int nf = 0; nf < 4; ++nf)
#pragma unroll
                    for (int i = 0; i < 4; ++i) {
                        float sc = sf[mi][nf][i] * SCALE;
                        if (needMask && (t * 64 + nf * 16 + lg * 4 + i) > qrow)
                            sc = -1e30f;
                        sf[mi][nf][i] = sc;
                        mt = fmaxf(mt, sc);
                    }
                mt = fmaxf(mt, __shfl_xor(mt, 16));
                mt = fmaxf(mt, __shfl_xor(mt, 32));
                float mnew = fmaxf(mrow[mi], mt);
                float alpha = __expf(mrow[mi] - mnew);
                mrow[mi] = mnew;
                float rs = 0.f;
#pragma unroll
                for (int nf = 0; nf < 4; ++nf)
#pragma unroll
                    for (int i = 0; i < 4; ++i) {
                        float p = __expf(sf[mi][nf][i] - mnew);
                        sf[mi][nf][i] = p;
                        rs += p;
                    }
                rs += __shfl_xor(rs, 16);
                rs += __shfl_xor(rs, 32);
                lsum[mi] = lsum[mi] * alpha + rs;
#pragma unroll
                for (int i = 0; i < 4; ++i)
                    aO[mi][i] = __shfl(alpha, lg * 4 + i);
            }

#pragma unroll
            for (int mi = 0; mi < 2; ++mi)
#pragma unroll
                for (int df = 0; df < 8; ++df)
#pragma unroll
                    for (int i = 0; i < 4; ++i)
                        oacc[mi][df][i] *= aO[mi][i];

#pragma unroll
            for (int mi = 0; mi < 2; ++mi)
#pragma unroll
                for (int nf = 0; nf < 4; ++nf) {
                    union { bf16_t bb[4]; uint2 u; } pk;
#pragma unroll
                    for (int i = 0; i < 4; ++i) pk.bb[i] = (bf16_t)sf[mi][nf][i];
                    int addr = (mi * 16 + lr) * 64 +
                               (((nf * 2 + (lg >> 1)) ^ e) << 3) + (lg & 1) * 4;
                    *(uint2*)(&Ps[w][addr]) = pk.u;
                }
            asm volatile("s_waitcnt lgkmcnt(0)" ::: "memory");
            __builtin_amdgcn_sched_barrier(0);

            bf16x8 pf[2][2];
#pragma unroll
            for (int mi = 0; mi < 2; ++mi)
#pragma unroll
                for (int k2 = 0; k2 < 2; ++k2)
                    pf[mi][k2] = *(const bf16x8*)(
                        &Ps[w][(mi * 16 + lr) * 64 + ((k2 * 4 + lg) ^ e) * 8]);
#pragma unroll
            for (int df = 0; df < 8; ++df)
#pragma unroll
                for (int k2 = 0; k2 < 2; ++k2) {
                    bf16x8 vf = *(const bf16x8*)(
                        &Vs[cur][(df * 16 + lr) * 64 + ((k2 * 4 + lg) ^ e) * 8]);
#pragma unroll
                    for (int mi = 0; mi < 2; ++mi)
                        oacc[mi][df] = __builtin_amdgcn_mfma_f32_16x16x32_bf16(
                            pf[mi][k2], vf, oacc[mi][df], 0, 0, 0);
                }
        }
        __syncthreads();
        cur ^= 1;
    }

#pragma unroll
    for (int mi = 0; mi < 2; ++mi) {
        float ls[4];
#pragma unroll
        for (int i = 0; i < 4; ++i)
            ls[i] = 1.f / __shfl(lsum[mi], lg * 4 + i);
#pragma unroll
        for (int df = 0; df < 8; ++df)
#pragma unroll
            for (int i = 0; i < 4; ++i) {
                float o = oacc[mi][df][i] * ls[i];
                int gm = b * SEQ + qmin + mi * 16 + lg * 4 + i;
                int gn = h * HD + df * 16 + lr;
                Ob[(size_t)gm * DIM + gn] = (bf16_t)o;
            }
    }
}

// ---------------- launcher ----------------
extern "C" void kernel_launch(void* const* d_in, const int* in_sizes, int n_in,
                              void* d_out, int out_size, void* d_ws, size_t ws_size,
                              hipStream_t stream) {
    const float* x    = (const float*)d_in[0];
    const float* cosT = (const float*)d_in[1];
    const float* sinT = (const float*)d_in[2];
    const float* wq   = (const float*)d_in[3];
    const float* wk   = (const float*)d_in[4];
    const float* wv   = (const float*)d_in[5];
    const float* wo   = (const float*)d_in[6];

    bf16_t* p = (bf16_t*)d_ws;
    bf16_t* xb  = p; p += (size_t)MTOT * DIM;
    bf16_t* wqb = p; p += (size_t)DIM * DIM;
    bf16_t* wkb = p; p += (size_t)NKVH * HD * DIM;
    bf16_t* wvb = p; p += (size_t)NKVH * HD * DIM;
    bf16_t* wob = p; p += (size_t)DIM * DIM;
    bf16_t* Qr  = p; p += (size_t)MTOT * DIM;
    bf16_t* Kr  = p; p += (size_t)BATCH * NKVH * SEQ * HD;
    bf16_t* Vt  = p; p += (size_t)BATCH * NKVH * HD * SEQ;
    bf16_t* Ob  = p; p += (size_t)MTOT * DIM;

    cvt_f32_bf16<<<2048, 256, 0, stream>>>(x, xb, MTOT * DIM / 4);
    cvt_weights<<<2048, 256, 0, stream>>>(wq, wk, wv, wo, wqb);

    gemm8<1><<<dim3(16, 16), 512, 0, stream>>>(
        xb, wqb, nullptr, nullptr, Qr, nullptr, cosT, sinT);
    gemm8<2><<<dim3(16, 8), 512, 0, stream>>>(
        xb, wkb, wvb, nullptr, Kr, Vt, cosT, sinT);

    attn_fwd<<<1024, 256, 0, stream>>>(Qr, Kr, Vt, Ob);

    gemm8<0><<<dim3(16, 16), 512, 0, stream>>>(
        Ob, wob, nullptr, (float*)d_out, nullptr, nullptr, nullptr, nullptr);
}